// Round 10
// baseline (296.813 us; speedup 1.0000x reference)
//
#include <hip/hip_runtime.h>
#include <math.h>

#define NN 100000
#define NE 1600000
#define CH  128
#define CO  18
#define NPB 256                        // nodes per bucket (dst >> 8)
#define NBUK ((NN + NPB - 1) / NPB)    // 391
#define EPB 4096                       // edges per k_bin block
#define NBB ((NE + EPB - 1) / EPB)     // 391

typedef unsigned int uint;
typedef unsigned short ushort;
typedef float floatx4 __attribute__((ext_vector_type(4)));
typedef short short8 __attribute__((ext_vector_type(8)));
typedef ushort ushort4v __attribute__((ext_vector_type(4)));

// ---- bf16 helpers ----
__device__ __forceinline__ float bf_lo(uint u) { return __uint_as_float(u << 16); }
__device__ __forceinline__ float bf_hi(uint u) { return __uint_as_float(u & 0xFFFF0000u); }
__device__ __forceinline__ ushort f2bf(float f) {
    uint u = __float_as_uint(f);
    u += 0x7FFFu + ((u >> 16) & 1u);        // RNE
    return (ushort)(u >> 16);
}
__device__ __forceinline__ uint pack_bf16(float a, float b) {
    return (uint)f2bf(a) | ((uint)f2bf(b) << 16);
}

// ---------------- node degree count ----------------

__global__ __launch_bounds__(256) void k_count(const int* __restrict__ dst,
                                               int* __restrict__ counts) {
    int stride = gridDim.x * 256;
    for (int e = blockIdx.x * 256 + threadIdx.x; e < NE; e += stride)
        atomicAdd(&counts[dst[e]], 1);
}

// ---------------- dinv + bucket counts (LDS reduce, no atomics) -------------

__global__ __launch_bounds__(256) void k_dinv_bcnt(const int* __restrict__ counts,
                                                   float* __restrict__ dinv,
                                                   int* __restrict__ bcnt) {
    __shared__ int s[256];
    int tid = threadIdx.x;
    int i = blockIdx.x * 256 + tid;
    int c = (i < NN) ? counts[i] : 0;
    if (i < NN) dinv[i] = rsqrtf((float)c + 1.0f);   // +1 self-loop
    s[tid] = c;
    __syncthreads();
    for (int off = 128; off > 0; off >>= 1) {
        if (tid < off) s[tid] += s[tid + off];
        __syncthreads();
    }
    if (tid == 0) bcnt[blockIdx.x] = s[0];
}

__global__ __launch_bounds__(512) void k_bscan(const int* __restrict__ bcnt,
                                               int* __restrict__ bbase,
                                               int* __restrict__ bcur) {
    __shared__ int s[512];
    int tid = threadIdx.x;
    int c = (tid < NBUK) ? bcnt[tid] : 0;
    s[tid] = c;
    __syncthreads();
    for (int off = 1; off < 512; off <<= 1) {
        int t = (tid >= off) ? s[tid - off] : 0;
        __syncthreads();
        s[tid] += t;
        __syncthreads();
    }
    if (tid < NBUK) {
        int ex = s[tid] - c;
        bbase[tid] = ex;
        bcur[tid] = ex;
    }
    if (tid == NBUK) bbase[NBUK] = NE;
}

// ---------------- fat B: bin (blocks 0..NBB-1) || gemm1s (rest) -------------
// gemm1s: h1s(bf16) = dinv[row] * (x @ W1)  -- pre-scaled by src-side norm.

union FatBLDS {
    struct { int h[NBUK]; int base[NBUK]; } b;
    struct { ushort As[128 * 128]; ushort Bs[128 * 128]; } g;
};

__global__ __launch_bounds__(256, 2) void k_fatB(const int* __restrict__ src,
                                                 const int* __restrict__ dst,
                                                 int* __restrict__ bcur,
                                                 uint* __restrict__ etmp,
                                                 const float* __restrict__ x,
                                                 const float* __restrict__ W1,
                                                 const float* __restrict__ dinv,
                                                 ushort* __restrict__ h1s) {
    __shared__ FatBLDS L;
    int tid = threadIdx.x;

    if (blockIdx.x < NBB) {
        // ---- bin: packed record (src<<8)|(dst&255) ----
        for (int i = tid; i < NBUK; i += 256) L.b.h[i] = 0;
        __syncthreads();
        int e0 = blockIdx.x * EPB;
        int sv[EPB / 256], dv[EPB / 256];
#pragma unroll
        for (int i = 0; i < EPB / 256; ++i) {
            int e = e0 + i * 256 + tid;
            if (e < NE) {
                sv[i] = src[e];
                dv[i] = dst[e];
                atomicAdd(&L.b.h[dv[i] >> 8], 1);
            } else {
                dv[i] = -1;
            }
        }
        __syncthreads();
        for (int i = tid; i < NBUK; i += 256)
            L.b.base[i] = L.b.h[i] ? atomicAdd(&bcur[i], L.b.h[i]) : 0;
        __syncthreads();
        for (int i = tid; i < NBUK; i += 256) L.b.h[i] = 0;
        __syncthreads();
#pragma unroll
        for (int i = 0; i < EPB / 256; ++i) {
            if (dv[i] >= 0) {
                int b = dv[i] >> 8;
                int pos = L.b.base[b] + atomicAdd(&L.b.h[b], 1);
                etmp[pos] = ((uint)sv[i] << 8) | ((uint)dv[i] & 255u);
            }
        }
        return;
    }

    // ---- gemm1s (MFMA) ----
    int row0 = (blockIdx.x - NBB) * 128;

    // stage W1 fp32 [k][n] -> Bs bf16 [n][k] swizzled
    for (int p = tid; p < 8192; p += 256) {
        int kp = p >> 7, n = p & 127;
        float w0 = W1[(2 * kp) * 128 + n];
        float w1 = W1[(2 * kp + 1) * 128 + n];
        ((uint*)L.g.Bs)[(n * 64 + kp) ^ ((n & 7) << 2)] = pack_bf16(w0, w1);
    }
    // stage x rows -> As bf16 swizzled
    for (int i = 0; i < 16; ++i) {
        int flat = i * 256 + tid;
        int r = flat >> 5, c4 = flat & 31;
        int gr = row0 + r;
        float4 v = (gr < NN) ? ((const float4*)x)[(size_t)gr * 32 + c4]
                             : make_float4(0.f, 0.f, 0.f, 0.f);
        ushort4v p;
        p.x = f2bf(v.x); p.y = f2bf(v.y); p.z = f2bf(v.z); p.w = f2bf(v.w);
        int idx = (r * 128 + c4 * 4) ^ ((r & 7) << 3);
        *(ushort4v*)&L.g.As[idx] = p;
    }
    __syncthreads();

    int lane = tid & 63;
    int wave = tid >> 6;
    int wrow = wave * 32;
    int lr = lane & 15;
    int lk8 = (lane >> 4) * 8;

    floatx4 acc[2][8];
#pragma unroll
    for (int a = 0; a < 2; ++a)
#pragma unroll
        for (int b = 0; b < 8; ++b) acc[a][b] = (floatx4)(0.0f);

#pragma unroll
    for (int ks = 0; ks < 4; ++ks) {
        int k0 = ks * 32 + lk8;
        int r0r = wrow + lr;
        int r1r = wrow + 16 + lr;
        short8 a0 = *(const short8*)&L.g.As[(r0r * 128 + k0) ^ ((r0r & 7) << 3)];
        short8 a1 = *(const short8*)&L.g.As[(r1r * 128 + k0) ^ ((r1r & 7) << 3)];
#pragma unroll
        for (int nt = 0; nt < 8; ++nt) {
            int n = nt * 16 + lr;
            short8 bf = *(const short8*)&L.g.Bs[(n * 128 + k0) ^ ((n & 7) << 3)];
            acc[0][nt] = __builtin_amdgcn_mfma_f32_16x16x32_bf16(a0, bf, acc[0][nt], 0, 0, 0);
            acc[1][nt] = __builtin_amdgcn_mfma_f32_16x16x32_bf16(a1, bf, acc[1][nt], 0, 0, 0);
        }
    }

    int drow = (lane >> 4) * 4;
#pragma unroll
    for (int rt = 0; rt < 2; ++rt) {
#pragma unroll
        for (int i = 0; i < 4; ++i) {
            int gr = row0 + wrow + rt * 16 + drow + i;
            if (gr < NN) {
                float dv = dinv[gr];
                uint base = (uint)gr * 128u;
#pragma unroll
                for (int nt = 0; nt < 8; ++nt)
                    h1s[base + nt * 16 + lr] = f2bf(acc[rt][nt][i] * dv);
            }
        }
    }
}

// ---------------- pass2: row_start + distribute (hist from counts) ----------

__global__ __launch_bounds__(256) void k_pass2(const int* __restrict__ bbase,
                                               const int* __restrict__ counts,
                                               const uint* __restrict__ etmp,
                                               int* __restrict__ row_start,
                                               int* __restrict__ csr_src) {
    __shared__ int s[NPB];
    __shared__ int cur[NPB];
    int tid = threadIdx.x;
    int b = blockIdx.x;
    int e0 = bbase[b], e1 = bbase[b + 1];

    int node = b * NPB + tid;
    int c = (node < NN) ? counts[node] : 0;
    s[tid] = c;
    __syncthreads();
    for (int off = 1; off < 256; off <<= 1) {
        int t = (tid >= off) ? s[tid - off] : 0;
        __syncthreads();
        s[tid] += t;
        __syncthreads();
    }
    int pfx = s[tid] - c;
    s[tid] = pfx;
    cur[tid] = 0;

    if (node < NN) row_start[node] = e0 + pfx;
    if (b == NBUK - 1 && tid == 0) row_start[NN] = NE;
    __syncthreads();

    for (int e = e0 + tid; e < e1; e += 256) {
        uint r = etmp[e];
        int n = (int)(r & 255u);
        int p = e0 + s[n] + atomicAdd(&cur[n], 1);
        csr_src[p] = (int)(r >> 8);
    }
}

// ------- agg1: pure row-sum gather (rows pre-scaled), final x dinv ----------
// one wave per node (128-thr blocks), 8-edge unroll, 32-bit offsets

__global__ __launch_bounds__(128) void k_agg1(const int* __restrict__ row_start,
                                              const int* __restrict__ csr_src,
                                              const float* __restrict__ dinv,
                                              const uint* __restrict__ h1u,
                                              const float* __restrict__ b1,
                                              uint* __restrict__ h1ru) {
    int wave = threadIdx.x >> 6;
    int lane = threadIdx.x & 63;
    int i = blockIdx.x * 2 + wave;
    if (i >= NN) return;
    int r0 = row_start[i], r1 = row_start[i + 1];
    float ax = 0.0f, ay = 0.0f;

    int j = r0;
    for (; j + 7 < r1; j += 8) {
        int s0 = csr_src[j],     s1 = csr_src[j + 1];
        int s2 = csr_src[j + 2], s3 = csr_src[j + 3];
        int s4 = csr_src[j + 4], s5 = csr_src[j + 5];
        int s6 = csr_src[j + 6], s7 = csr_src[j + 7];
        uint u0 = h1u[(uint)s0 * 64u + lane];
        uint u1 = h1u[(uint)s1 * 64u + lane];
        uint u2 = h1u[(uint)s2 * 64u + lane];
        uint u3 = h1u[(uint)s3 * 64u + lane];
        uint u4 = h1u[(uint)s4 * 64u + lane];
        uint u5 = h1u[(uint)s5 * 64u + lane];
        uint u6 = h1u[(uint)s6 * 64u + lane];
        uint u7 = h1u[(uint)s7 * 64u + lane];
        ax += (bf_lo(u0) + bf_lo(u1)) + (bf_lo(u2) + bf_lo(u3))
            + (bf_lo(u4) + bf_lo(u5)) + (bf_lo(u6) + bf_lo(u7));
        ay += (bf_hi(u0) + bf_hi(u1)) + (bf_hi(u2) + bf_hi(u3))
            + (bf_hi(u4) + bf_hi(u5)) + (bf_hi(u6) + bf_hi(u7));
    }
    for (; j < r1; ++j) {
        uint u0 = h1u[(uint)csr_src[j] * 64u + lane];
        ax += bf_lo(u0);
        ay += bf_hi(u0);
    }

    // self-loop: h1s[i] already = dinv[i]*h1[i]
    uint us = h1u[(uint)i * 64u + lane];
    ax += bf_lo(us);
    ay += bf_hi(us);

    float di = dinv[i];
    float2 bb = ((const float2*)b1)[lane];
    float ox = fmaxf(ax * di + bb.x, 0.0f);
    float oy = fmaxf(ay * di + bb.y, 0.0f);
    h1ru[(uint)i * 64u + lane] = pack_bf16(ox, oy);
}

// ------- GEMM2s: h2s(bf16) = dinv[row] * (h1r @ W2) ; rows 12 uints (48B) ---

__global__ __launch_bounds__(256, 2) void k_gemm2(const uint* __restrict__ h1ru,
                                                  const float* __restrict__ W2,
                                                  const float* __restrict__ dinv,
                                                  ushort* __restrict__ h2b) {
    __shared__ float xs[128][129];
    __shared__ float Ws[128 * 18];
    int row0 = blockIdx.x * 128;
    int tid = threadIdx.x;

    for (int i = tid; i < 128 * 18; i += 256) Ws[i] = W2[i];
    for (int i = tid; i < 128 * 64; i += 256) {
        int r = i >> 6, c2 = i & 63;
        int gr = row0 + r;
        uint u = (gr < NN) ? h1ru[(uint)gr * 64u + c2] : 0u;
        xs[r][2 * c2]     = bf_lo(u);
        xs[r][2 * c2 + 1] = bf_hi(u);
    }
    __syncthreads();

    int rl   = tid & 127;
    int half = tid >> 7;
    int j0   = half * 9;
    float acc[9];
#pragma unroll
    for (int j = 0; j < 9; ++j) acc[j] = 0.0f;

#pragma unroll 4
    for (int k = 0; k < 128; ++k) {
        float xv = xs[rl][k];
#pragma unroll
        for (int j = 0; j < 9; ++j)
            acc[j] += xv * Ws[k * 18 + j0 + j];
    }
    int gr = row0 + rl;
    if (gr < NN) {
        float dv = dinv[gr];
#pragma unroll
        for (int j = 0; j < 9; ++j)
            h2b[(uint)gr * 24u + j0 + j] = f2bf(acc[j] * dv);
        if (half) {
#pragma unroll
            for (int j = 0; j < 6; ++j)
                h2b[(uint)gr * 24u + 18 + j] = 0;     // zero pads
        }
    }
}

// ------- agg2: 2 threads/node, pure row-sum, final x dinv + log_softmax -----

__device__ __forceinline__ void add6(float* acc, uint4 av, uint2 cv) {
    acc[0]  += bf_lo(av.x); acc[1]  += bf_hi(av.x);
    acc[2]  += bf_lo(av.y); acc[3]  += bf_hi(av.y);
    acc[4]  += bf_lo(av.z); acc[5]  += bf_hi(av.z);
    acc[6]  += bf_lo(av.w); acc[7]  += bf_hi(av.w);
    acc[8]  += bf_lo(cv.x); acc[9]  += bf_hi(cv.x);
    acc[10] += bf_lo(cv.y); acc[11] += bf_hi(cv.y);
}

__global__ __launch_bounds__(256) void k_agg2(const int* __restrict__ row_start,
                                              const int* __restrict__ csr_src,
                                              const float* __restrict__ dinv,
                                              const uint* __restrict__ h2u,   // 12 uints/row
                                              const float* __restrict__ b2,
                                              float* __restrict__ out) {
    int t = blockIdx.x * 256 + threadIdx.x;
    int i = t >> 1;
    int half = t & 1;
    if (i >= NN) return;
    int r0 = row_start[i], r1 = row_start[i + 1];
    uint base = (uint)half * 6u;
    float acc[12];
#pragma unroll
    for (int j = 0; j < 12; ++j) acc[j] = 0.0f;

    int e = r0;
    for (; e + 3 < r1; e += 4) {
        int s0 = csr_src[e],     s1 = csr_src[e + 1];
        int s2 = csr_src[e + 2], s3 = csr_src[e + 3];
        const uint* p0 = h2u + (uint)s0 * 12u + base;
        const uint* p1 = h2u + (uint)s1 * 12u + base;
        const uint* p2 = h2u + (uint)s2 * 12u + base;
        const uint* p3 = h2u + (uint)s3 * 12u + base;
        uint4 a0 = *(const uint4*)p0; uint2 c0 = *(const uint2*)(p0 + 4);
        uint4 a1 = *(const uint4*)p1; uint2 c1 = *(const uint2*)(p1 + 4);
        uint4 a2 = *(const uint4*)p2; uint2 c2 = *(const uint2*)(p2 + 4);
        uint4 a3 = *(const uint4*)p3; uint2 c3 = *(const uint2*)(p3 + 4);
        add6(acc, a0, c0);
        add6(acc, a1, c1);
        add6(acc, a2, c2);
        add6(acc, a3, c3);
    }
    for (; e < r1; ++e) {
        const uint* p = h2u + (uint)csr_src[e] * 12u + base;
        uint4 a = *(const uint4*)p; uint2 c = *(const uint2*)(p + 4);
        add6(acc, a, c);
    }

    // self-loop (h2s[i] already dinv-scaled)
    const uint* pi = h2u + (uint)i * 12u + base;
    uint4 ia = *(const uint4*)pi; uint2 ic = *(const uint2*)(pi + 4);
    add6(acc, ia, ic);

    float di = dinv[i];
    int ch0 = half * 12;
    float m = -1e30f;
#pragma unroll
    for (int j = 0; j < 12; ++j) {
        int ch = ch0 + j;
        if (ch < CO) {
            acc[j] = acc[j] * di + b2[ch];
            m = fmaxf(m, acc[j]);
        }
    }
    m = fmaxf(m, __shfl_xor(m, 1));
    float sum = 0.0f;
#pragma unroll
    for (int j = 0; j < 12; ++j) {
        int ch = ch0 + j;
        if (ch < CO) sum += expf(acc[j] - m);
    }
    sum += __shfl_xor(sum, 1);
    float lse = logf(sum);
    float* op = out + (size_t)i * CO;
#pragma unroll
    for (int j = 0; j < 12; ++j) {
        int ch = ch0 + j;
        if (ch < CO) op[ch] = acc[j] - m - lse;
    }
}

// ---------------- launch ----------------

extern "C" void kernel_launch(void* const* d_in, const int* in_sizes, int n_in,
                              void* d_out, int out_size, void* d_ws, size_t ws_size,
                              hipStream_t stream) {
    const float* x  = (const float*)d_in[0];
    const int*   ei = (const int*)d_in[1];
    const float* W1 = (const float*)d_in[2];
    const float* b1 = (const float*)d_in[3];
    const float* W2 = (const float*)d_in[4];
    const float* b2 = (const float*)d_in[5];
    float* out = (float*)d_out;

    const int* src = ei;
    const int* dst = ei + NE;

    // workspace layout (~70 MB)
    uint* h1u  = (uint*)d_ws;                        // N*64 uints (h1s bf16 pairs)
    uint* h1ru = h1u + (size_t)NN * 64;              // N*64 (relu'd layer-1 out)
    uint* h2u  = h1ru + (size_t)NN * 64;             // N*12 (h2s, 18 bf16 + pad)
    float* dinv = (float*)(h2u + (size_t)NN * 12);   // N
    int* counts    = (int*)(dinv + NN);              // N
    int* row_start = counts + NN;                    // N+1
    int* csr_src   = row_start + NN + 1;             // E
    uint* etmp     = (uint*)(csr_src + NE);          // E packed records
    int* bcnt      = (int*)(etmp + NE);              // NBUK
    int* bbase     = bcnt + NBUK;                    // NBUK+1
    int* bcur      = bbase + NBUK + 1;               // NBUK

    hipMemsetAsync(counts, 0, (size_t)NN * sizeof(int), stream);

    k_count<<<2048, 256, 0, stream>>>(dst, counts);
    k_dinv_bcnt<<<NBUK, 256, 0, stream>>>(counts, dinv, bcnt);
    k_bscan<<<1, 512, 0, stream>>>(bcnt, bbase, bcur);
    // fatB: bin (391 blocks) || gemm1s (782 blocks)
    k_fatB<<<NBB + (NN + 127) / 128, 256, 0, stream>>>(src, dst, bcur, etmp,
                                                       x, W1, dinv, (ushort*)h1u);
    k_pass2<<<NBUK, 256, 0, stream>>>(bbase, counts, etmp, row_start, csr_src);

    k_agg1<<<(NN + 1) / 2, 128, 0, stream>>>(row_start, csr_src, dinv, h1u, b1, h1ru);
    k_gemm2<<<(NN + 127) / 128, 256, 0, stream>>>(h1ru, W2, dinv, (ushort*)h2u);
    k_agg2<<<(2 * NN + 255) / 256, 256, 0, stream>>>(row_start, csr_src, dinv, h2u, b2, out);
}

// Round 11
// 249.026 us; speedup vs baseline: 1.1919x; 1.1919x over previous
//
#include <hip/hip_runtime.h>
#include <math.h>

#define NN 100000
#define NE 1600000
#define CH  128
#define CO  18
#define NPB 256                        // nodes per bucket (dst >> 8)
#define NBUK ((NN + NPB - 1) / NPB)    // 391
#define EPB 4096                       // edges per k_bin block
#define NBB ((NE + EPB - 1) / EPB)     // 391

typedef unsigned int uint;
typedef unsigned short ushort;
typedef float floatx4 __attribute__((ext_vector_type(4)));
typedef short short8 __attribute__((ext_vector_type(8)));
typedef ushort ushort4v __attribute__((ext_vector_type(4)));

// ---- bf16 helpers ----
__device__ __forceinline__ float bf_lo(uint u) { return __uint_as_float(u << 16); }
__device__ __forceinline__ float bf_hi(uint u) { return __uint_as_float(u & 0xFFFF0000u); }
__device__ __forceinline__ ushort f2bf(float f) {
    uint u = __float_as_uint(f);
    u += 0x7FFFu + ((u >> 16) & 1u);        // RNE
    return (ushort)(u >> 16);
}
__device__ __forceinline__ uint pack_bf16(float a, float b) {
    return (uint)f2bf(a) | ((uint)f2bf(b) << 16);
}

// ---------------- fat K1: bhist (blocks 0..NBB-1)  ||  gemm1 (rest) --------
// gemm1 converts W1 fp32 -> bf16 during staging (no wprep kernel).

union FatLDS {
    int h[NBUK];
    struct { ushort As[128 * 128]; ushort Bs[128 * 128]; } g;
};

__global__ __launch_bounds__(256, 2) void k_fat1(const int* __restrict__ dst,
                                                 int* __restrict__ bcnt,
                                                 const float* __restrict__ x,
                                                 const float* __restrict__ W1,
                                                 ushort* __restrict__ h1s) {
    __shared__ FatLDS L;
    int tid = threadIdx.x;

    if (blockIdx.x < NBB) {
        // ---- bucket histogram ----
        for (int i = tid; i < NBUK; i += 256) L.h[i] = 0;
        __syncthreads();
        int e0 = blockIdx.x * EPB;
#pragma unroll
        for (int i = 0; i < EPB / 256; ++i) {
            int e = e0 + i * 256 + tid;
            if (e < NE) atomicAdd(&L.h[dst[e] >> 8], 1);
        }
        __syncthreads();
        for (int i = tid; i < NBUK; i += 256)
            if (L.h[i]) atomicAdd(&bcnt[i], L.h[i]);
        return;
    }

    // ---- gemm1 (MFMA): h1(bf16) = x @ W1 ----
    int row0 = (blockIdx.x - NBB) * 128;

    // stage W1 fp32 [k][n] -> Bs bf16 [n][k] swizzled
    for (int p = tid; p < 8192; p += 256) {
        int kp = p >> 7, n = p & 127;          // kp = k-pair
        float w0 = W1[(2 * kp) * 128 + n];
        float w1 = W1[(2 * kp + 1) * 128 + n];
        ((uint*)L.g.Bs)[(n * 64 + kp) ^ ((n & 7) << 2)] = pack_bf16(w0, w1);
    }
    // stage x rows -> As bf16 swizzled
    for (int i = 0; i < 16; ++i) {
        int flat = i * 256 + tid;
        int r = flat >> 5, c4 = flat & 31;
        int gr = row0 + r;
        float4 v = (gr < NN) ? ((const float4*)x)[(size_t)gr * 32 + c4]
                             : make_float4(0.f, 0.f, 0.f, 0.f);
        ushort4v p;
        p.x = f2bf(v.x); p.y = f2bf(v.y); p.z = f2bf(v.z); p.w = f2bf(v.w);
        int idx = (r * 128 + c4 * 4) ^ ((r & 7) << 3);
        *(ushort4v*)&L.g.As[idx] = p;
    }
    __syncthreads();

    int lane = tid & 63;
    int wave = tid >> 6;
    int wrow = wave * 32;
    int lr = lane & 15;
    int lk8 = (lane >> 4) * 8;

    floatx4 acc[2][8];
#pragma unroll
    for (int a = 0; a < 2; ++a)
#pragma unroll
        for (int b = 0; b < 8; ++b) acc[a][b] = (floatx4)(0.0f);

#pragma unroll
    for (int ks = 0; ks < 4; ++ks) {
        int k0 = ks * 32 + lk8;
        int r0r = wrow + lr;
        int r1r = wrow + 16 + lr;
        short8 a0 = *(const short8*)&L.g.As[(r0r * 128 + k0) ^ ((r0r & 7) << 3)];
        short8 a1 = *(const short8*)&L.g.As[(r1r * 128 + k0) ^ ((r1r & 7) << 3)];
#pragma unroll
        for (int nt = 0; nt < 8; ++nt) {
            int n = nt * 16 + lr;
            short8 bf = *(const short8*)&L.g.Bs[(n * 128 + k0) ^ ((n & 7) << 3)];
            acc[0][nt] = __builtin_amdgcn_mfma_f32_16x16x32_bf16(a0, bf, acc[0][nt], 0, 0, 0);
            acc[1][nt] = __builtin_amdgcn_mfma_f32_16x16x32_bf16(a1, bf, acc[1][nt], 0, 0, 0);
        }
    }

    int drow = (lane >> 4) * 4;
#pragma unroll
    for (int rt = 0; rt < 2; ++rt) {
#pragma unroll
        for (int i = 0; i < 4; ++i) {
            int gr = row0 + wrow + rt * 16 + drow + i;
            if (gr < NN) {
                size_t base = (size_t)gr * 128;
#pragma unroll
                for (int nt = 0; nt < 8; ++nt)
                    h1s[base + nt * 16 + lr] = f2bf(acc[rt][nt][i]);
            }
        }
    }
}

// ---------------- CSR build (rest) ----------------

__global__ __launch_bounds__(512) void k_bscan(const int* __restrict__ bcnt,
                                               int* __restrict__ bbase,
                                               int* __restrict__ bcur) {
    __shared__ int s[512];
    int tid = threadIdx.x;
    int c = (tid < NBUK) ? bcnt[tid] : 0;
    s[tid] = c;
    __syncthreads();
    for (int off = 1; off < 512; off <<= 1) {
        int t = (tid >= off) ? s[tid - off] : 0;
        __syncthreads();
        s[tid] += t;
        __syncthreads();
    }
    if (tid < NBUK) {
        int ex = s[tid] - c;
        bbase[tid] = ex;
        bcur[tid] = ex;
    }
    if (tid == NBUK) bbase[NBUK] = NE;
}

// packed record: (src << 8) | (dst & 255)
__global__ __launch_bounds__(256) void k_bin(const int* __restrict__ src,
                                             const int* __restrict__ dst,
                                             int* __restrict__ bcur,
                                             uint* __restrict__ etmp) {
    __shared__ int h[NBUK];
    __shared__ int base[NBUK];
    int tid = threadIdx.x;
    for (int i = tid; i < NBUK; i += 256) h[i] = 0;
    __syncthreads();

    int e0 = blockIdx.x * EPB;
    int sv[EPB / 256], dv[EPB / 256];
#pragma unroll
    for (int i = 0; i < EPB / 256; ++i) {
        int e = e0 + i * 256 + tid;
        if (e < NE) {
            sv[i] = src[e];
            dv[i] = dst[e];
            atomicAdd(&h[dv[i] >> 8], 1);
        } else {
            dv[i] = -1;
        }
    }
    __syncthreads();
    for (int i = tid; i < NBUK; i += 256)
        base[i] = h[i] ? atomicAdd(&bcur[i], h[i]) : 0;
    __syncthreads();
    for (int i = tid; i < NBUK; i += 256) h[i] = 0;
    __syncthreads();
#pragma unroll
    for (int i = 0; i < EPB / 256; ++i) {
        if (dv[i] >= 0) {
            int b = dv[i] >> 8;
            int pos = base[b] + atomicAdd(&h[b], 1);
            etmp[pos] = ((uint)sv[i] << 8) | ((uint)dv[i] & 255u);
        }
    }
}

__global__ __launch_bounds__(256) void k_pass2(const int* __restrict__ bbase,
                                               const uint* __restrict__ etmp,
                                               int* __restrict__ row_start,
                                               float* __restrict__ dinv,
                                               int* __restrict__ csr_src) {
    __shared__ int hist[NPB];
    __shared__ int s[NPB];
    __shared__ int cur[NPB];
    int tid = threadIdx.x;
    int b = blockIdx.x;
    int e0 = bbase[b], e1 = bbase[b + 1];

    hist[tid] = 0;
    __syncthreads();
    for (int e = e0 + tid; e < e1; e += 256)
        atomicAdd(&hist[etmp[e] & 255u], 1);
    __syncthreads();

    int c = hist[tid];
    s[tid] = c;
    __syncthreads();
    for (int off = 1; off < 256; off <<= 1) {
        int t = (tid >= off) ? s[tid - off] : 0;
        __syncthreads();
        s[tid] += t;
        __syncthreads();
    }
    int pfx = s[tid] - c;
    s[tid] = pfx;
    cur[tid] = 0;

    int node = b * NPB + tid;
    if (node < NN) {
        row_start[node] = e0 + pfx;
        dinv[node] = rsqrtf((float)c + 1.0f);
    }
    if (b == NBUK - 1 && tid == 0) row_start[NN] = NE;
    __syncthreads();

    for (int e = e0 + tid; e < e1; e += 256) {
        uint r = etmp[e];
        int n = (int)(r & 255u);
        int p = e0 + s[n] + atomicAdd(&cur[n], 1);
        csr_src[p] = (int)(r >> 8);
    }
}

// ------- agg1 (CSR gather, bf16 rows) + self-loop + bias + relu -> bf16 -----
// one wave per node (4 nodes / 256-thr block), 8-edge unroll

__global__ __launch_bounds__(256) void k_agg1(const int* __restrict__ row_start,
                                              const int* __restrict__ csr_src,
                                              const float* __restrict__ dinv,
                                              const uint* __restrict__ h1u,
                                              const float* __restrict__ b1,
                                              uint* __restrict__ h1ru) {
    int wave = threadIdx.x >> 6;
    int lane = threadIdx.x & 63;
    int i = blockIdx.x * 4 + wave;
    if (i >= NN) return;
    int r0 = row_start[i], r1 = row_start[i + 1];
    float di = dinv[i];
    float ax = 0.0f, ay = 0.0f;

    int j = r0;
    for (; j + 7 < r1; j += 8) {
        int s0 = csr_src[j],     s1 = csr_src[j + 1];
        int s2 = csr_src[j + 2], s3 = csr_src[j + 3];
        int s4 = csr_src[j + 4], s5 = csr_src[j + 5];
        int s6 = csr_src[j + 6], s7 = csr_src[j + 7];
        float w0 = dinv[s0] * di, w1 = dinv[s1] * di;
        float w2 = dinv[s2] * di, w3 = dinv[s3] * di;
        float w4 = dinv[s4] * di, w5 = dinv[s5] * di;
        float w6 = dinv[s6] * di, w7 = dinv[s7] * di;
        uint u0 = h1u[(size_t)s0 * 64 + lane];
        uint u1 = h1u[(size_t)s1 * 64 + lane];
        uint u2 = h1u[(size_t)s2 * 64 + lane];
        uint u3 = h1u[(size_t)s3 * 64 + lane];
        uint u4 = h1u[(size_t)s4 * 64 + lane];
        uint u5 = h1u[(size_t)s5 * 64 + lane];
        uint u6 = h1u[(size_t)s6 * 64 + lane];
        uint u7 = h1u[(size_t)s7 * 64 + lane];
        ax += w0 * bf_lo(u0) + w1 * bf_lo(u1) + w2 * bf_lo(u2) + w3 * bf_lo(u3)
            + w4 * bf_lo(u4) + w5 * bf_lo(u5) + w6 * bf_lo(u6) + w7 * bf_lo(u7);
        ay += w0 * bf_hi(u0) + w1 * bf_hi(u1) + w2 * bf_hi(u2) + w3 * bf_hi(u3)
            + w4 * bf_hi(u4) + w5 * bf_hi(u5) + w6 * bf_hi(u6) + w7 * bf_hi(u7);
    }
    for (; j < r1; ++j) {
        int s0 = csr_src[j];
        float w0 = dinv[s0] * di;
        uint u0 = h1u[(size_t)s0 * 64 + lane];
        ax += w0 * bf_lo(u0);
        ay += w0 * bf_hi(u0);
    }

    uint us = h1u[(size_t)i * 64 + lane];
    float2 bb = ((const float2*)b1)[lane];
    float di2 = di * di;
    float ox = fmaxf(ax + di2 * bf_lo(us) + bb.x, 0.0f);
    float oy = fmaxf(ay + di2 * bf_hi(us) + bb.y, 0.0f);
    h1ru[(size_t)i * 64 + lane] = pack_bf16(ox, oy);
}

// ------- GEMM2: h2b(bf16) = h1r(bf16) @ W2 ; rows strided 24 ushorts (48B) --

__global__ __launch_bounds__(256, 2) void k_gemm2(const uint* __restrict__ h1ru,
                                                  const float* __restrict__ W2,
                                                  ushort* __restrict__ h2b) {
    __shared__ float xs[128][129];
    __shared__ float Ws[128 * 18];
    int row0 = blockIdx.x * 128;
    int tid = threadIdx.x;

    for (int i = tid; i < 128 * 18; i += 256) Ws[i] = W2[i];
    for (int i = tid; i < 128 * 64; i += 256) {
        int r = i >> 6, c2 = i & 63;
        int gr = row0 + r;
        uint u = (gr < NN) ? h1ru[(size_t)gr * 64 + c2] : 0u;
        xs[r][2 * c2]     = bf_lo(u);
        xs[r][2 * c2 + 1] = bf_hi(u);
    }
    __syncthreads();

    int rl   = tid & 127;
    int half = tid >> 7;
    int j0   = half * 9;
    float acc[9];
#pragma unroll
    for (int j = 0; j < 9; ++j) acc[j] = 0.0f;

#pragma unroll 4
    for (int k = 0; k < 128; ++k) {
        float xv = xs[rl][k];
#pragma unroll
        for (int j = 0; j < 9; ++j)
            acc[j] += xv * Ws[k * 18 + j0 + j];
    }
    int gr = row0 + rl;
    if (gr < NN) {
#pragma unroll
        for (int j = 0; j < 9; ++j)
            h2b[(size_t)gr * 24 + j0 + j] = f2bf(acc[j]);   // stride 24 ushorts
    }
}

// ------- agg2 (CSR gather, 48B-strided bf16 rows) + bias + log_softmax ------
// 1 thread/node, 4-edge unroll, rows read as 2x uint4 + 1x uint (9 uints)

__device__ __forceinline__ void acc_row(float* acc, float wgt,
                                        uint4 av, uint4 bv, uint cv) {
    acc[0]  += wgt * bf_lo(av.x); acc[1]  += wgt * bf_hi(av.x);
    acc[2]  += wgt * bf_lo(av.y); acc[3]  += wgt * bf_hi(av.y);
    acc[4]  += wgt * bf_lo(av.z); acc[5]  += wgt * bf_hi(av.z);
    acc[6]  += wgt * bf_lo(av.w); acc[7]  += wgt * bf_hi(av.w);
    acc[8]  += wgt * bf_lo(bv.x); acc[9]  += wgt * bf_hi(bv.x);
    acc[10] += wgt * bf_lo(bv.y); acc[11] += wgt * bf_hi(bv.y);
    acc[12] += wgt * bf_lo(bv.z); acc[13] += wgt * bf_hi(bv.z);
    acc[14] += wgt * bf_lo(bv.w); acc[15] += wgt * bf_hi(bv.w);
    acc[16] += wgt * bf_lo(cv);   acc[17] += wgt * bf_hi(cv);
}

__global__ __launch_bounds__(256) void k_agg2(const int* __restrict__ row_start,
                                              const int* __restrict__ csr_src,
                                              const float* __restrict__ dinv,
                                              const uint* __restrict__ h2u,   // 12 uints/row
                                              const float* __restrict__ b2,
                                              float* __restrict__ out) {
    int i = blockIdx.x * 256 + threadIdx.x;
    if (i >= NN) return;
    int r0 = row_start[i], r1 = row_start[i + 1];
    float di = dinv[i];
    float acc[CO];
#pragma unroll
    for (int j = 0; j < CO; ++j) acc[j] = 0.0f;

    int e = r0;
    for (; e + 3 < r1; e += 4) {
        int s0 = csr_src[e],     s1 = csr_src[e + 1];
        int s2 = csr_src[e + 2], s3 = csr_src[e + 3];
        float w0 = dinv[s0] * di, w1 = dinv[s1] * di;
        float w2 = dinv[s2] * di, w3 = dinv[s3] * di;
        const uint* p0 = h2u + (size_t)s0 * 12;
        const uint* p1 = h2u + (size_t)s1 * 12;
        const uint* p2 = h2u + (size_t)s2 * 12;
        const uint* p3 = h2u + (size_t)s3 * 12;
        uint4 a0 = *(const uint4*)p0, b0 = *(const uint4*)(p0 + 4); uint c0 = p0[8];
        uint4 a1 = *(const uint4*)p1, b1v = *(const uint4*)(p1 + 4); uint c1 = p1[8];
        uint4 a2 = *(const uint4*)p2, b2v = *(const uint4*)(p2 + 4); uint c2 = p2[8];
        uint4 a3 = *(const uint4*)p3, b3v = *(const uint4*)(p3 + 4); uint c3 = p3[8];
        acc_row(acc, w0, a0, b0, c0);
        acc_row(acc, w1, a1, b1v, c1);
        acc_row(acc, w2, a2, b2v, c2);
        acc_row(acc, w3, a3, b3v, c3);
    }
    for (; e < r1; ++e) {
        int s = csr_src[e];
        float w = dinv[s] * di;
        const uint* p = h2u + (size_t)s * 12;
        uint4 a = *(const uint4*)p, b = *(const uint4*)(p + 4); uint c = p[8];
        acc_row(acc, w, a, b, c);
    }

    float di2 = di * di;
    const uint* pi = h2u + (size_t)i * 12;
    uint4 ia = *(const uint4*)pi, ib = *(const uint4*)(pi + 4); uint ic = pi[8];
    acc_row(acc, di2, ia, ib, ic);

    float m = -1e30f;
#pragma unroll
    for (int j = 0; j < CO; ++j) {
        acc[j] += b2[j];
        m = fmaxf(m, acc[j]);
    }
    float sum = 0.0f;
#pragma unroll
    for (int j = 0; j < CO; ++j) sum += expf(acc[j] - m);
    float lse = logf(sum);
    float* op = out + (size_t)i * CO;
#pragma unroll
    for (int j = 0; j < CO; ++j) op[j] = acc[j] - m - lse;
}

// ---------------- launch ----------------

extern "C" void kernel_launch(void* const* d_in, const int* in_sizes, int n_in,
                              void* d_out, int out_size, void* d_ws, size_t ws_size,
                              hipStream_t stream) {
    const float* x  = (const float*)d_in[0];
    const int*   ei = (const int*)d_in[1];
    const float* W1 = (const float*)d_in[2];
    const float* b1 = (const float*)d_in[3];
    const float* W2 = (const float*)d_in[4];
    const float* b2 = (const float*)d_in[5];
    float* out = (float*)d_out;

    const int* src = ei;
    const int* dst = ei + NE;

    // workspace layout (~73 MB)
    uint* h1u  = (uint*)d_ws;                        // N*64 uints (bf16 pairs)
    uint* h1ru = h1u + (size_t)NN * 64;              // N*64
    uint* h2u  = h1ru + (size_t)NN * 64;             // N*12 (18 bf16 + pad)
    float* dinv = (float*)(h2u + (size_t)NN * 12);   // N
    int* row_start = (int*)(dinv + NN);              // N+1
    int* csr_src   = row_start + NN + 1;             // E
    uint* etmp     = (uint*)(csr_src + NE);          // E packed records
    int* bcnt      = (int*)(etmp + NE);              // NBUK
    int* bbase     = bcnt + NBUK;                    // NBUK+1
    int* bcur      = bbase + NBUK + 1;               // NBUK

    hipMemsetAsync(bcnt, 0, NBUK * sizeof(int), stream);

    // K1: bhist (391 blocks) || gemm1 (782 blocks)
    k_fat1<<<NBB + (NN + 127) / 128, 256, 0, stream>>>(dst, bcnt, x, W1, (ushort*)h1u);
    k_bscan<<<1, 512, 0, stream>>>(bcnt, bbase, bcur);
    k_bin<<<NBB, 256, 0, stream>>>(src, dst, bcur, etmp);
    k_pass2<<<NBUK, 256, 0, stream>>>(bbase, etmp, row_start, dinv, csr_src);

    k_agg1<<<(NN + 3) / 4, 256, 0, stream>>>(row_start, csr_src, dinv, h1u, b1, h1ru);
    k_gemm2<<<(NN + 127) / 128, 256, 0, stream>>>(h1ru, W2, (ushort*)h2u);
    k_agg2<<<(NN + 255) / 256, 256, 0, stream>>>(row_start, csr_src, dinv, h2u, b2, out);
}